// Round 11
// baseline (639.442 us; speedup 1.0000x reference)
//
#include <hip/hip_runtime.h>

// LSTMForecaster: B=4096, T=512, D=1, H=64, 2 layers + FC(64->1).
// R11: finer-grained free-running waves. R10 showed pipes still summing:
//   3 waves/SIMD, L1 twins phase-identical, L1 triggered directly off L0's
//   publish -> all waves in same phase. Fixes:
//   (1) 16 waves (1024 thr): 8 L0 x 8 units (8 MFMA + 1 cell2) + 8 L1 x 8
//       units (16 MFMA + 1 cell2); 2 L0 + 2 L1 per SIMD = 4 streams.
//   (2) L1 split burst: Whh1*h1(t-1) right after f1 poll (f0-independent),
//       THEN poll f0 (pre-satisfied in steady state; L0 runs ~8 ahead on the
//       ring) and do Wih1*h0(t) -> MFMA de-phased around the VALU leg.
//   Sync/ring/math invariants unchanged from R10 (passed, absmax 1.22e-4):
//   h0 ring 8 slots, h1 ring 2, monotone flags gate full-step completion.

#define TT 512
#define HH 64
#define NB 16
#define XP 516

typedef __bf16 bf16_t;
typedef bf16_t bf16x8 __attribute__((ext_vector_type(8)));
typedef float  f32x4  __attribute__((ext_vector_type(4)));
typedef float  f32x2  __attribute__((ext_vector_type(2)));

#define MFMA(A, B, C) __builtin_amdgcn_mfma_f32_16x16x32_bf16((A), (B), (C), 0, 0, 0)
#define RCPF(x) __builtin_amdgcn_rcpf(x)

#if __has_builtin(__builtin_amdgcn_exp2f)
#define EXP2F(x) __builtin_amdgcn_exp2f(x)
#else
__device__ __forceinline__ float EXP2F(float x) {
    float r;
    asm volatile("v_exp_f32 %0, %1" : "=v"(r) : "v"(x));
    return r;
}
#endif

#define SC_IFO (-1.4426950408889634f)   // -log2(e)
#define SC_G   ( 2.8853900817779268f)   // +2*log2(e)

__device__ __forceinline__ unsigned short f32_to_bf16_rne(float f) {
    unsigned int u = __builtin_bit_cast(unsigned int, f);
    unsigned int r = u + 0x7fffu + ((u >> 16) & 1u);
    return (unsigned short)(r >> 16);
}
__device__ __forceinline__ float bf16bits_to_f32(unsigned short s) {
    return __builtin_bit_cast(float, ((unsigned int)s) << 16);
}
__device__ __forceinline__ bf16_t bits_to_bf16(unsigned short u) {
    return __builtin_bit_cast(bf16_t, u);
}
__device__ __forceinline__ void build_frags_scaled(const float* __restrict__ p, float sc,
                                                   bf16x8& hi, bf16x8& lo) {
    const float4 a = *(const float4*)p;
    const float4 b = *(const float4*)(p + 4);
    float v[8] = {a.x, a.y, a.z, a.w, b.x, b.y, b.z, b.w};
#pragma unroll
    for (int jj = 0; jj < 8; ++jj) {
        const float s = v[jj] * sc;
        unsigned short h = f32_to_bf16_rne(s);
        float d = s - bf16bits_to_f32(h);
        hi[jj] = bits_to_bf16(h);
        lo[jj] = bits_to_bf16(f32_to_bf16_rne(d));
    }
}

__device__ __forceinline__ f32x2 exp2v(f32x2 v) {
    f32x2 r; r[0] = EXP2F(v[0]); r[1] = EXP2F(v[1]); return r;
}
__device__ __forceinline__ f32x2 rcpv(f32x2 v) {
    f32x2 r; r[0] = RCPF(v[0]); r[1] = RCPF(v[1]); return r;
}
// Two cells on PRE-SCALED gates (is,fs,os scaled -log2e; gs scaled +2log2e).
__device__ __forceinline__ f32x2 cell2(const f32x4 a0, const f32x4 a1, f32x2* c) {
    f32x2 is = {a0[0], a1[0]}, fs = {a0[1], a1[1]};
    f32x2 gs = {a0[2], a1[2]}, os = {a0[3], a1[3]};
    const f32x2 pf = exp2v(fs);
    const f32x2 fg = rcpv(1.0f + pf);
    const f32x2 pi = exp2v(is);
    const f32x2 e2 = exp2v(gs);
    const f32x2 z  = (e2 - 1.0f) * rcpv((1.0f + pi) * (1.0f + e2));
    *c = fg * (*c) + z;
    const f32x2 po  = exp2v(os);
    const f32x2 e2c = exp2v((*c) * SC_G);
    return (e2c - 1.0f) * rcpv((1.0f + po) * (1.0f + e2c));
}

__device__ __forceinline__ int imin2(int a, int b) { return a < b ? a : b; }
__device__ __forceinline__ int min8(const int* f) {
    const int4 a = *(const int4*)f;
    const int4 b = *(const int4*)(f + 4);
    return imin2(imin2(imin2(a.x, a.y), imin2(a.z, a.w)),
                 imin2(imin2(b.x, b.y), imin2(b.z, b.w)));
}

__global__ __launch_bounds__(1024, 4)
void lstm_ff16_kernel(const float* __restrict__ x,
                      const float* __restrict__ Wih0, const float* __restrict__ Whh0,
                      const float* __restrict__ bih0, const float* __restrict__ bhh0,
                      const float* __restrict__ Wih1, const float* __restrict__ Whh1,
                      const float* __restrict__ bih1, const float* __restrict__ bhh1,
                      const float* __restrict__ Wfc,  const float* __restrict__ bfc,
                      float* __restrict__ out)
{
    __shared__ float xbuf[NB][XP];                   // 33 KB
    __shared__ unsigned short h0r[8][NB][64];        // 16 KB ring, slot t&7
    __shared__ unsigned short h1r[2][NB][64];        // 4 KB ring, slot t&1
    __shared__ float h1fin[HH][NB + 1];              // 4.25 KB
    __shared__ __align__(16) int f0[8];              // L0 wave progress flags
    __shared__ __align__(16) int f1[8];              // L1 wave progress flags

    const int tid  = threadIdx.x;
    const int wv   = tid >> 6;       // 0..15: 0-7 L0 waves, 8-15 L1 waves
    const int lane = tid & 63;
    const int m    = lane & 15;      // batch col (B/C frag) & A-frag row-in-tile
    const int q    = lane >> 4;      // C-frag unit_local; A/B k-quad
    const int m7   = m & 7;
    const int b0   = blockIdx.x * NB;
    const bool isL0 = (wv < 8);

    // ---- stage x (coalesced float4) ----
    for (int i = tid; i < NB * TT / 4; i += 1024) {
        const int b  = i >> 7;
        const int t4 = i & 127;
        *(float4*)&xbuf[b][t4 * 4] = *(const float4*)&x[(size_t)(b0 + b) * TT + t4 * 4];
    }
    // ---- zero rings (h(-1) served by zeroed slots) + flags ----
    for (int i = tid; i < 8 * NB * 64; i += 1024) (&h0r[0][0][0])[i] = 0;
    for (int i = tid; i < 2 * NB * 64; i += 1024) (&h1r[0][0][0])[i] = 0;
    if (tid < 8) f0[tid] = -1;
    else if (tid < 16) f1[tid - 8] = -1;

    // ---- per-lane read offsets (shorts within one slot = 1024) ----
    int roff[2];
#pragma unroll
    for (int kt = 0; kt < 2; ++kt)
        roff[kt] = m * 64 + (((4 * kt + q) ^ m7) * 8);

    const int gate_m = m & 3;
    const float scA  = (gate_m == 2) ? SC_G : SC_IFO;
    unsigned short* const H0 = &h0r[0][0][0];
    unsigned short* const H1 = &h1r[0][0][0];

    __syncthreads();     // the ONLY barrier before the epilogue

    if (isL0) {
        // ===== L0 waves: units [8w,8w+8), 2 unit-major tiles, 8 MFMA =====
        const int w = wv;
        bf16x8 Ah[2][2], Al[2][2];          // [tau][kt] of Whh0
        f32x4 bb0s[2], wx0s[2];
        int woff[2];
#pragma unroll
        for (int tau = 0; tau < 2; ++tau) {
            const int rowA = 64 * gate_m + 8 * w + 4 * tau + (m >> 2);
#pragma unroll
            for (int kt = 0; kt < 2; ++kt)
                build_frags_scaled(&Whh0[rowA * HH + kt * 32 + q * 8], scA,
                                   Ah[tau][kt], Al[tau][kt]);
#pragma unroll
            for (int r = 0; r < 4; ++r) {
                const int row = 64 * r + 8 * w + 4 * tau + q;
                const float sc = (r == 2) ? SC_G : SC_IFO;
                bb0s[tau][r] = (bih0[row] + bhh0[row]) * sc;
                wx0s[tau][r] = Wih0[row] * sc;
            }
            const int u = 8 * w + 4 * tau + q;
            woff[tau] = m * 64 + (((u >> 3) ^ m7) * 8) + (u & 7);
        }

        f32x2 cA = {0.f, 0.f};

#pragma unroll 1
        for (int t = 0; t < TT; ++t) {
            // ---- wait for h0(t-1) complete (all 8 L0 waves) ----
            while (true) {
                if (min8(f0) >= t - 1) break;
                asm volatile("" ::: "memory");
                __builtin_amdgcn_s_sleep(1);
            }
            asm volatile("" ::: "memory");

            const int rs = ((t - 1) & 7) * (NB * 64);
            bf16x8 h0[2];
            h0[0] = *(const bf16x8*)(H0 + rs + roff[0]);
            h0[1] = *(const bf16x8*)(H0 + rs + roff[1]);
            const float xv = xbuf[m][t];

            f32x4 a[2];
#pragma unroll
            for (int tau = 0; tau < 2; ++tau) {
                f32x4 p;
#pragma unroll
                for (int r = 0; r < 4; ++r)
                    p[r] = __builtin_fmaf(xv, wx0s[tau][r], bb0s[tau][r]);
                f32x4 z = {0.f, 0.f, 0.f, 0.f};
                p = MFMA(Ah[tau][0], h0[0], p);
                p = MFMA(Al[tau][0], h0[0], p);
                z = MFMA(Ah[tau][1], h0[1], z);
                z = MFMA(Al[tau][1], h0[1], z);
                a[tau] = p + z;
            }

            // ---- back-pressure: slot t&7 (h0(t-8)) fully consumed by L1 ----
            while (true) {
                if (min8(f1) >= t - 8) break;
                asm volatile("" ::: "memory");
                __builtin_amdgcn_s_sleep(1);
            }
            asm volatile("" ::: "memory");

            const f32x2 hv = cell2(a[0], a[1], &cA);
            const int ws = (t & 7) * (NB * 64);
            H0[ws + woff[0]] = f32_to_bf16_rne(hv[0]);
            H0[ws + woff[1]] = f32_to_bf16_rne(hv[1]);

            asm volatile("s_waitcnt lgkmcnt(0)" ::: "memory");
            if (lane == 0) *(volatile int*)&f0[w] = t;
        }
    } else {
        // ===== L1 waves: units [8u,8u+8), 2 tiles, 16 MFMA (split bursts) =====
        const int u1 = wv - 8;
        bf16x8 Bih[2][2], Bil[2][2];     // Wih1 (eats h0(t))
        bf16x8 Bhh[2][2], Bhl[2][2];     // Whh1 (eats h1(t-1))
        f32x4 bb1s[2];
        int woff[2], uu[2];
#pragma unroll
        for (int tau = 0; tau < 2; ++tau) {
            const int rowA = 64 * gate_m + 8 * u1 + 4 * tau + (m >> 2);
#pragma unroll
            for (int kt = 0; kt < 2; ++kt)
                build_frags_scaled(&Wih1[rowA * HH + kt * 32 + q * 8], scA,
                                   Bih[tau][kt], Bil[tau][kt]);
#pragma unroll
            for (int kt = 0; kt < 2; ++kt)
                build_frags_scaled(&Whh1[rowA * HH + kt * 32 + q * 8], scA,
                                   Bhh[tau][kt], Bhl[tau][kt]);
#pragma unroll
            for (int r = 0; r < 4; ++r) {
                const int row = 64 * r + 8 * u1 + 4 * tau + q;
                const float sc = (r == 2) ? SC_G : SC_IFO;
                bb1s[tau][r] = (bih1[row] + bhh1[row]) * sc;
            }
            const int u = 8 * u1 + 4 * tau + q;
            uu[tau]   = u;
            woff[tau] = m * 64 + (((u >> 3) ^ m7) * 8) + (u & 7);
        }

        f32x2 c1 = {0.f, 0.f};

#pragma unroll 1
        for (int t = 0; t < TT; ++t) {
            // ---- burst 1: Whh1 . h1(t-1) (only needs f1 >= t-1) ----
            while (true) {
                if (min8(f1) >= t - 1) break;
                asm volatile("" ::: "memory");
                __builtin_amdgcn_s_sleep(1);
            }
            asm volatile("" ::: "memory");
            const int rs1 = ((t - 1) & 1) * (NB * 64);
            bf16x8 h1[2];
            h1[0] = *(const bf16x8*)(H1 + rs1 + roff[0]);
            h1[1] = *(const bf16x8*)(H1 + rs1 + roff[1]);

            f32x4 s[2];
#pragma unroll
            for (int tau = 0; tau < 2; ++tau) {
                f32x4 acc = bb1s[tau];
                acc = MFMA(Bhh[tau][0], h1[0], acc);
                acc = MFMA(Bhl[tau][0], h1[0], acc);
                acc = MFMA(Bhh[tau][1], h1[1], acc);
                acc = MFMA(Bhl[tau][1], h1[1], acc);
                s[tau] = acc;
            }

            // ---- burst 2: Wih1 . h0(t) (needs f0 >= t; pre-satisfied when
            //      L0 runs ahead on the 8-deep ring) ----
            while (true) {
                if (min8(f0) >= t) break;
                asm volatile("" ::: "memory");
                __builtin_amdgcn_s_sleep(1);
            }
            asm volatile("" ::: "memory");
            const int rs0 = (t & 7) * (NB * 64);
            bf16x8 h0[2];
            h0[0] = *(const bf16x8*)(H0 + rs0 + roff[0]);
            h0[1] = *(const bf16x8*)(H0 + rs0 + roff[1]);

            f32x4 a[2];
#pragma unroll
            for (int tau = 0; tau < 2; ++tau) {
                f32x4 p = {0.f, 0.f, 0.f, 0.f};
                p = MFMA(Bih[tau][0], h0[0], p);
                p = MFMA(Bil[tau][0], h0[0], p);
                p = MFMA(Bih[tau][1], h0[1], p);
                p = MFMA(Bil[tau][1], h0[1], p);
                a[tau] = p + s[tau];
            }

            const f32x2 hv = cell2(a[0], a[1], &c1);
            if (t == TT - 1) {                  // exact fp32 h1(T-1) for FC
                h1fin[uu[0]][m] = hv[0];
                h1fin[uu[1]][m] = hv[1];
            }
            const int ws = (t & 1) * (NB * 64);
            H1[ws + woff[0]] = f32_to_bf16_rne(hv[0]);
            H1[ws + woff[1]] = f32_to_bf16_rne(hv[1]);

            asm volatile("s_waitcnt lgkmcnt(0)" ::: "memory");
            if (lane == 0) *(volatile int*)&f1[u1] = t;
        }
    }

    __syncthreads();

    // ---- FC epilogue: out[b] = h1(T-1)[b] . Wfc + bfc ----
    if (tid < NB) {
        float sacc = bfc[0];
#pragma unroll
        for (int u = 0; u < HH; ++u) sacc = fmaf(h1fin[u][tid], Wfc[u], sacc);
        out[b0 + tid] = sacc;
    }
}

extern "C" void kernel_launch(void* const* d_in, const int* in_sizes, int n_in,
                              void* d_out, int out_size, void* d_ws, size_t ws_size,
                              hipStream_t stream) {
    const float* x    = (const float*)d_in[0];
    const float* Wih0 = (const float*)d_in[1];
    const float* Whh0 = (const float*)d_in[2];
    const float* bih0 = (const float*)d_in[3];
    const float* bhh0 = (const float*)d_in[4];
    const float* Wih1 = (const float*)d_in[5];
    const float* Whh1 = (const float*)d_in[6];
    const float* bih1 = (const float*)d_in[7];
    const float* bhh1 = (const float*)d_in[8];
    const float* Wfc  = (const float*)d_in[9];
    const float* bfc  = (const float*)d_in[10];

    lstm_ff16_kernel<<<dim3(4096 / NB), dim3(1024), 0, stream>>>(
        x, Wih0, Whh0, bih0, bhh0, Wih1, Whh1, bih1, bhh1, Wfc, bfc, (float*)d_out);
}

// Round 12
// 536.696 us; speedup vs baseline: 1.1914x; 1.1914x over previous
//
#include <hip/hip_runtime.h>

// LSTMForecaster: B=4096, T=512, D=1, H=64, 2 layers + FC(64->1).
// R12 = R10 (best: 519us) + targeted idle cuts. R11 (more waves) regressed:
//   poll traffic up, per-wave work down, spin instability at 4 waves/SIMD.
//   R10 idle was 41%: two SERIAL 120-cyc flag reads per L1 step + coupling.
//   Steady state: L0 (8 MFMA) is faster than L1 (16 MFMA) -> L0 runs to ring
//   limit; h0 is the SLACK input, h1 the TIGHT one. Cuts:
//   (1) h0 ring 32 slots (64KB), h1 ring 4 slots -> ~30 steps of slack.
//   (2) monotone-flag caching: cached min is a forever-valid lower bound;
//       L1's f0 check and L0's f1 back-pressure refresh ~1/30 steps.
//   (3) L1 burst reorder: h0-burst (slack-gated) FIRST, f1 poll + h1-burst +
//       cell LAST -> tight tail minimized.
//   Structure/math = R10: 12 waves (4 L0 x 16u, 8 L1 x 8u), 2-term W-split
//   GEMM, single-bf16 h, exp2-folded scales, packed cells, absmax 1.22e-4.

#define TT 512
#define HH 64
#define NB 16
#define XP 516

typedef __bf16 bf16_t;
typedef bf16_t bf16x8 __attribute__((ext_vector_type(8)));
typedef float  f32x4  __attribute__((ext_vector_type(4)));
typedef float  f32x2  __attribute__((ext_vector_type(2)));

#define MFMA(A, B, C) __builtin_amdgcn_mfma_f32_16x16x32_bf16((A), (B), (C), 0, 0, 0)
#define RCPF(x) __builtin_amdgcn_rcpf(x)

#if __has_builtin(__builtin_amdgcn_exp2f)
#define EXP2F(x) __builtin_amdgcn_exp2f(x)
#else
__device__ __forceinline__ float EXP2F(float x) {
    float r;
    asm volatile("v_exp_f32 %0, %1" : "=v"(r) : "v"(x));
    return r;
}
#endif

#define SC_IFO (-1.4426950408889634f)   // -log2(e)
#define SC_G   ( 2.8853900817779268f)   // +2*log2(e)

__device__ __forceinline__ unsigned short f32_to_bf16_rne(float f) {
    unsigned int u = __builtin_bit_cast(unsigned int, f);
    unsigned int r = u + 0x7fffu + ((u >> 16) & 1u);
    return (unsigned short)(r >> 16);
}
__device__ __forceinline__ float bf16bits_to_f32(unsigned short s) {
    return __builtin_bit_cast(float, ((unsigned int)s) << 16);
}
__device__ __forceinline__ bf16_t bits_to_bf16(unsigned short u) {
    return __builtin_bit_cast(bf16_t, u);
}
__device__ __forceinline__ void build_frags_scaled(const float* __restrict__ p, float sc,
                                                   bf16x8& hi, bf16x8& lo) {
    const float4 a = *(const float4*)p;
    const float4 b = *(const float4*)(p + 4);
    float v[8] = {a.x, a.y, a.z, a.w, b.x, b.y, b.z, b.w};
#pragma unroll
    for (int jj = 0; jj < 8; ++jj) {
        const float s = v[jj] * sc;
        unsigned short h = f32_to_bf16_rne(s);
        float d = s - bf16bits_to_f32(h);
        hi[jj] = bits_to_bf16(h);
        lo[jj] = bits_to_bf16(f32_to_bf16_rne(d));
    }
}

__device__ __forceinline__ f32x2 exp2v(f32x2 v) {
    f32x2 r; r[0] = EXP2F(v[0]); r[1] = EXP2F(v[1]); return r;
}
__device__ __forceinline__ f32x2 rcpv(f32x2 v) {
    f32x2 r; r[0] = RCPF(v[0]); r[1] = RCPF(v[1]); return r;
}
// Two cells on PRE-SCALED gates (is,fs,os scaled -log2e; gs scaled +2log2e).
__device__ __forceinline__ f32x2 cell2(const f32x4 a0, const f32x4 a1, f32x2* c) {
    f32x2 is = {a0[0], a1[0]}, fs = {a0[1], a1[1]};
    f32x2 gs = {a0[2], a1[2]}, os = {a0[3], a1[3]};
    const f32x2 pf = exp2v(fs);
    const f32x2 fg = rcpv(1.0f + pf);
    const f32x2 pi = exp2v(is);
    const f32x2 e2 = exp2v(gs);
    const f32x2 z  = (e2 - 1.0f) * rcpv((1.0f + pi) * (1.0f + e2));
    *c = fg * (*c) + z;
    const f32x2 po  = exp2v(os);
    const f32x2 e2c = exp2v((*c) * SC_G);
    return (e2c - 1.0f) * rcpv((1.0f + po) * (1.0f + e2c));
}

__device__ __forceinline__ int imin2(int a, int b) { return a < b ? a : b; }
__device__ __forceinline__ int min4of(const int* f) {
    const int4 v = *(const int4*)f;
    return imin2(imin2(v.x, v.y), imin2(v.z, v.w));
}
__device__ __forceinline__ int min8of(const int* f) {
    const int4 a = *(const int4*)f;
    const int4 b = *(const int4*)(f + 4);
    return imin2(imin2(imin2(a.x, a.y), imin2(a.z, a.w)),
                 imin2(imin2(b.x, b.y), imin2(b.z, b.w)));
}

__global__ __launch_bounds__(768, 3)
void lstm_ff32_kernel(const float* __restrict__ x,
                      const float* __restrict__ Wih0, const float* __restrict__ Whh0,
                      const float* __restrict__ bih0, const float* __restrict__ bhh0,
                      const float* __restrict__ Wih1, const float* __restrict__ Whh1,
                      const float* __restrict__ bih1, const float* __restrict__ bhh1,
                      const float* __restrict__ Wfc,  const float* __restrict__ bfc,
                      float* __restrict__ out)
{
    __shared__ float xbuf[NB][XP];                   // 33 KB
    __shared__ unsigned short h0r[32][NB][64];       // 64 KB ring, slot t&31
    __shared__ unsigned short h1r[4][NB][64];        // 8 KB ring, slot t&3
    __shared__ float h1fin[HH][NB + 1];              // 4.25 KB
    __shared__ __align__(16) int f0[4];              // L0 wave progress flags
    __shared__ __align__(16) int f1[8];              // L1 wave progress flags

    const int tid  = threadIdx.x;
    const int wv   = tid >> 6;       // 0..11: 0-3 L0 waves, 4-11 L1 waves
    const int lane = tid & 63;
    const int m    = lane & 15;      // batch col (B/C frag) & A-frag row-in-tile
    const int q    = lane >> 4;      // C-frag unit_local; A/B k-quad
    const int m7   = m & 7;
    const int b0   = blockIdx.x * NB;
    const bool isL0 = (wv < 4);

    // ---- stage x (coalesced float4) ----
    for (int i = tid; i < NB * TT / 4; i += 768) {
        const int b  = i >> 7;
        const int t4 = i & 127;
        *(float4*)&xbuf[b][t4 * 4] = *(const float4*)&x[(size_t)(b0 + b) * TT + t4 * 4];
    }
    // ---- zero rings (h(-1) served by zeroed slots) + flags ----
    for (int i = tid; i < 32 * NB * 64; i += 768) (&h0r[0][0][0])[i] = 0;
    for (int i = tid; i < 4 * NB * 64; i += 768) (&h1r[0][0][0])[i] = 0;
    if (tid < 4) f0[tid] = -1;
    else if (tid < 12) f1[tid - 4] = -1;

    // ---- per-lane read offsets (shorts within one slot = 1024) ----
    int roff[2];
#pragma unroll
    for (int kt = 0; kt < 2; ++kt)
        roff[kt] = m * 64 + (((4 * kt + q) ^ m7) * 8);

    const int gate_m = m & 3;
    const float scA  = (gate_m == 2) ? SC_G : SC_IFO;
    unsigned short* const H0 = &h0r[0][0][0];
    unsigned short* const H1 = &h1r[0][0][0];

    __syncthreads();     // the ONLY barrier before the epilogue

    if (isL0) {
        // ===== L0 waves: units [16w,16w+16), 4 unit-major tiles, 16 MFMA =====
        const int w = wv;
        bf16x8 Ah[4][2], Al[4][2];          // [tau][kt] of Whh0
        f32x4 bb0s[4], wx0s[4];
        int woff[4];
#pragma unroll
        for (int tau = 0; tau < 4; ++tau) {
            const int rowA = 64 * gate_m + 16 * w + 4 * tau + (m >> 2);
#pragma unroll
            for (int kt = 0; kt < 2; ++kt)
                build_frags_scaled(&Whh0[rowA * HH + kt * 32 + q * 8], scA,
                                   Ah[tau][kt], Al[tau][kt]);
#pragma unroll
            for (int r = 0; r < 4; ++r) {
                const int row = 64 * r + 16 * w + 4 * tau + q;
                const float sc = (r == 2) ? SC_G : SC_IFO;
                bb0s[tau][r] = (bih0[row] + bhh0[row]) * sc;
                wx0s[tau][r] = Wih0[row] * sc;
            }
            const int u = 16 * w + 4 * tau + q;
            woff[tau] = m * 64 + (((u >> 3) ^ m7) * 8) + (u & 7);
        }

        f32x2 cA = {0.f, 0.f}, cB = {0.f, 0.f};
        int lastf1 = -1;                   // cached min(f1), monotone

#pragma unroll 1
        for (int t = 0; t < TT; ++t) {
            // ---- tight: all L0 waves done with h0(t-1) ----
            while (min4of(f0) < t - 1) {
                asm volatile("" ::: "memory");
                __builtin_amdgcn_s_sleep(1);
            }
            asm volatile("" ::: "memory");
            // ---- slack (cached): slot t&31 consumed by L1 (f1 >= t-32) ----
            if (lastf1 < t - 32) {
                while (true) {
                    lastf1 = min8of(f1);
                    if (lastf1 >= t - 32) break;
                    asm volatile("" ::: "memory");
                    __builtin_amdgcn_s_sleep(1);
                }
                asm volatile("" ::: "memory");
            }

            const int rs = ((t - 1) & 31) * (NB * 64);
            bf16x8 h0[2];
            h0[0] = *(const bf16x8*)(H0 + rs + roff[0]);
            h0[1] = *(const bf16x8*)(H0 + rs + roff[1]);
            const float xv = xbuf[m][t];

            f32x4 a[4];
#pragma unroll
            for (int tau = 0; tau < 4; ++tau) {
                f32x4 p;
#pragma unroll
                for (int r = 0; r < 4; ++r)
                    p[r] = __builtin_fmaf(xv, wx0s[tau][r], bb0s[tau][r]);
                f32x4 z = {0.f, 0.f, 0.f, 0.f};
                p = MFMA(Ah[tau][0], h0[0], p);
                p = MFMA(Al[tau][0], h0[0], p);
                z = MFMA(Ah[tau][1], h0[1], z);
                z = MFMA(Al[tau][1], h0[1], z);
                a[tau] = p + z;
            }

            const f32x2 hv0 = cell2(a[0], a[1], &cA);
            const f32x2 hv1 = cell2(a[2], a[3], &cB);

            const int ws = (t & 31) * (NB * 64);
            H0[ws + woff[0]] = f32_to_bf16_rne(hv0[0]);
            H0[ws + woff[1]] = f32_to_bf16_rne(hv0[1]);
            H0[ws + woff[2]] = f32_to_bf16_rne(hv1[0]);
            H0[ws + woff[3]] = f32_to_bf16_rne(hv1[1]);

            asm volatile("s_waitcnt lgkmcnt(0)" ::: "memory");
            if (lane == 0) *(volatile int*)&f0[w] = t;
        }
    } else {
        // ===== L1 waves: units [8u,8u+8), 2 tiles, 16 MFMA, slack-first =====
        const int u1 = wv - 4;
        bf16x8 Bih[2][2], Bil[2][2];     // Wih1 (eats h0(t))
        bf16x8 Bhh[2][2], Bhl[2][2];     // Whh1 (eats h1(t-1))
        f32x4 bb1s[2];
        int woff[2], uu[2];
#pragma unroll
        for (int tau = 0; tau < 2; ++tau) {
            const int rowA = 64 * gate_m + 8 * u1 + 4 * tau + (m >> 2);
#pragma unroll
            for (int kt = 0; kt < 2; ++kt)
                build_frags_scaled(&Wih1[rowA * HH + kt * 32 + q * 8], scA,
                                   Bih[tau][kt], Bil[tau][kt]);
#pragma unroll
            for (int kt = 0; kt < 2; ++kt)
                build_frags_scaled(&Whh1[rowA * HH + kt * 32 + q * 8], scA,
                                   Bhh[tau][kt], Bhl[tau][kt]);
#pragma unroll
            for (int r = 0; r < 4; ++r) {
                const int row = 64 * r + 8 * u1 + 4 * tau + q;
                const float sc = (r == 2) ? SC_G : SC_IFO;
                bb1s[tau][r] = (bih1[row] + bhh1[row]) * sc;
            }
            const int u = 8 * u1 + 4 * tau + q;
            uu[tau]   = u;
            woff[tau] = m * 64 + (((u >> 3) ^ m7) * 8) + (u & 7);
        }

        f32x2 c1 = {0.f, 0.f};
        int lastf0 = -1;                   // cached min(f0), monotone

#pragma unroll 1
        for (int t = 0; t < TT; ++t) {
            // ---- slack burst: Wih1 . h0(t) (f0 >= t, cached ~30 steps) ----
            if (lastf0 < t) {
                while (true) {
                    lastf0 = min4of(f0);
                    if (lastf0 >= t) break;
                    asm volatile("" ::: "memory");
                    __builtin_amdgcn_s_sleep(1);
                }
                asm volatile("" ::: "memory");
            }
            const int rs0 = (t & 31) * (NB * 64);
            bf16x8 h0[2];
            h0[0] = *(const bf16x8*)(H0 + rs0 + roff[0]);
            h0[1] = *(const bf16x8*)(H0 + rs0 + roff[1]);

            f32x4 p[2];
#pragma unroll
            for (int tau = 0; tau < 2; ++tau) {
                f32x4 acc = bb1s[tau];
                acc = MFMA(Bih[tau][0], h0[0], acc);
                acc = MFMA(Bil[tau][0], h0[0], acc);
                acc = MFMA(Bih[tau][1], h0[1], acc);
                acc = MFMA(Bil[tau][1], h0[1], acc);
                p[tau] = acc;
            }

            // ---- tight tail: Whh1 . h1(t-1) + cell + publish ----
            while (min8of(f1) < t - 1) {
                asm volatile("" ::: "memory");
                __builtin_amdgcn_s_sleep(1);
            }
            asm volatile("" ::: "memory");
            const int rs1 = ((t - 1) & 3) * (NB * 64);
            bf16x8 h1[2];
            h1[0] = *(const bf16x8*)(H1 + rs1 + roff[0]);
            h1[1] = *(const bf16x8*)(H1 + rs1 + roff[1]);

            f32x4 a[2];
#pragma unroll
            for (int tau = 0; tau < 2; ++tau) {
                f32x4 s = {0.f, 0.f, 0.f, 0.f};
                s = MFMA(Bhh[tau][0], h1[0], s);
                s = MFMA(Bhl[tau][0], h1[0], s);
                s = MFMA(Bhh[tau][1], h1[1], s);
                s = MFMA(Bhl[tau][1], h1[1], s);
                a[tau] = p[tau] + s;
            }

            const f32x2 hv = cell2(a[0], a[1], &c1);
            if (t == TT - 1) {                  // exact fp32 h1(T-1) for FC
                h1fin[uu[0]][m] = hv[0];
                h1fin[uu[1]][m] = hv[1];
            }
            const int ws = (t & 3) * (NB * 64);
            H1[ws + woff[0]] = f32_to_bf16_rne(hv[0]);
            H1[ws + woff[1]] = f32_to_bf16_rne(hv[1]);

            asm volatile("s_waitcnt lgkmcnt(0)" ::: "memory");
            if (lane == 0) *(volatile int*)&f1[u1] = t;
        }
    }

    __syncthreads();

    // ---- FC epilogue: out[b] = h1(T-1)[b] . Wfc + bfc ----
    if (tid < NB) {
        float sacc = bfc[0];
#pragma unroll
        for (int u = 0; u < HH; ++u) sacc = fmaf(h1fin[u][tid], Wfc[u], sacc);
        out[b0 + tid] = sacc;
    }
}

extern "C" void kernel_launch(void* const* d_in, const int* in_sizes, int n_in,
                              void* d_out, int out_size, void* d_ws, size_t ws_size,
                              hipStream_t stream) {
    const float* x    = (const float*)d_in[0];
    const float* Wih0 = (const float*)d_in[1];
    const float* Whh0 = (const float*)d_in[2];
    const float* bih0 = (const float*)d_in[3];
    const float* bhh0 = (const float*)d_in[4];
    const float* Wih1 = (const float*)d_in[5];
    const float* Whh1 = (const float*)d_in[6];
    const float* bih1 = (const float*)d_in[7];
    const float* bhh1 = (const float*)d_in[8];
    const float* Wfc  = (const float*)d_in[9];
    const float* bfc  = (const float*)d_in[10];

    lstm_ff32_kernel<<<dim3(4096 / NB), dim3(768), 0, stream>>>(
        x, Wih0, Whh0, bih0, bhh0, Wih1, Whh1, bih1, bhh1, Wfc, bfc, (float*)d_out);
}